// Round 2
// baseline (689.317 us; speedup 1.0000x reference)
//
#include <hip/hip_runtime.h>

#define HD 16   // hidden dim
#define NC 4    // num classes
#define SCAN_B 256
#define CHUNK 2048          // elements per scan block (256 thr x 8)

// ---------- K1: in-degree histogram over targets ----------
__global__ void k_degree(const int* __restrict__ col, int* __restrict__ cnt, int E) {
    int i = blockIdx.x * blockDim.x + threadIdx.x;
    if (i < E) atomicAdd(&cnt[col[i]], 1);
}

// ---------- K2: dinv = rsqrt(deg+1); dx = dinv*x ----------
__global__ void k_dinv(const int* __restrict__ cnt, const float* __restrict__ x,
                       float* __restrict__ dinv, float* __restrict__ dx, int N) {
    int i = blockIdx.x * blockDim.x + threadIdx.x;
    if (i < N) {
        float d = rsqrtf((float)(cnt[i] + 1));
        dinv[i] = d;
        dx[i] = d * x[i];
    }
}

// ---------- scan pass 1: per-block exclusive scan + block sums ----------
__global__ void k_scan1(const int* __restrict__ cnt, int* __restrict__ off,
                        int* __restrict__ bsum, int N) {
    __shared__ int sd[SCAN_B];
    int t = threadIdx.x;
    int base = blockIdx.x * CHUNK + t * 8;
    int v[8];
    int s = 0;
    #pragma unroll
    for (int k = 0; k < 8; ++k) {
        v[k] = (base + k < N) ? cnt[base + k] : 0;
        s += v[k];
    }
    sd[t] = s;
    __syncthreads();
    #pragma unroll
    for (int o = 1; o < SCAN_B; o <<= 1) {
        int x = (t >= o) ? sd[t - o] : 0;
        __syncthreads();
        sd[t] += x;
        __syncthreads();
    }
    int run = sd[t] - s;  // exclusive prefix of this thread's 8
    #pragma unroll
    for (int k = 0; k < 8; ++k) {
        if (base + k < N) off[base + k] = run;
        run += v[k];
    }
    if (t == SCAN_B - 1) bsum[blockIdx.x] = sd[t];
}

// ---------- scan pass 2: exclusive scan of block sums (single block, NBLK<=256) ----------
__global__ void k_scan2(int* __restrict__ bsum, int NBLK) {
    __shared__ int sd[SCAN_B];
    int t = threadIdx.x;
    int v = (t < NBLK) ? bsum[t] : 0;
    sd[t] = v;
    __syncthreads();
    #pragma unroll
    for (int o = 1; o < SCAN_B; o <<= 1) {
        int x = (t >= o) ? sd[t - o] : 0;
        __syncthreads();
        sd[t] += x;
        __syncthreads();
    }
    if (t < NBLK) bsum[t] = sd[t] - v;  // exclusive
}

// ---------- scan pass 3: add block base; init fill cursors ----------
__global__ void k_scan3(int* __restrict__ off, const int* __restrict__ bsum,
                        int* __restrict__ fill, int N) {
    int i = blockIdx.x * blockDim.x + threadIdx.x;
    if (i < N) {
        int o = off[i] + bsum[i / CHUNK];
        off[i] = o;
        fill[i] = o;
    }
}

// ---------- K3: CSR build (counting-sort scatter of source ids by target) ----------
__global__ void k_build(const int* __restrict__ row, const int* __restrict__ col,
                        int* __restrict__ fill, int* __restrict__ csr, int E) {
    int i = blockIdx.x * blockDim.x + threadIdx.x;
    if (i < E) {
        int pos = atomicAdd(&fill[col[i]], 1);
        csr[pos] = row[i];
    }
}

// ---------- K4: layer-1 scalar aggregate, deterministic ----------
__global__ void k_s1(const int* __restrict__ off, const int* __restrict__ cnt,
                     const int* __restrict__ csr, const float* __restrict__ dinv,
                     const float* __restrict__ dx, float* __restrict__ s1, int N) {
    int i = blockIdx.x * blockDim.x + threadIdx.x;
    if (i >= N) return;
    int o = off[i], d = cnt[i];
    float s = 0.0f;
    for (int j = o; j < o + d; ++j) s += dx[csr[j]];
    s1[i] = dinv[i] * (s + dx[i]);  // + self-loop dinv^2 * x
}

// ---------- K5: fused layer-2 aggregate + W2/relu + Wfc epilogue ----------
__global__ void k_agg_out(const int* __restrict__ off, const int* __restrict__ cnt,
                          const int* __restrict__ csr, const float* __restrict__ dinv,
                          const float* __restrict__ s1,
                          const float* __restrict__ W1, const float* __restrict__ b1,
                          const float* __restrict__ W2, const float* __restrict__ b2,
                          const float* __restrict__ Wfc, const float* __restrict__ bfc,
                          float* __restrict__ out, int N) {
    int i = blockIdx.x * blockDim.x + threadIdx.x;
    if (i >= N) return;
    float w1[HD], bb1[HD];
    #pragma unroll
    for (int f = 0; f < HD; ++f) { w1[f] = W1[f]; bb1[f] = b1[f]; }
    float acc[HD];
    #pragma unroll
    for (int f = 0; f < HD; ++f) acc[f] = 0.0f;
    int o = off[i], d = cnt[i];
    for (int j = o; j < o + d; ++j) {
        int r = csr[j];
        float sv = s1[r], w = dinv[r];
        #pragma unroll
        for (int f = 0; f < HD; ++f)
            acc[f] = fmaf(w, fmaxf(fmaf(sv, w1[f], bb1[f]), 0.0f), acc[f]);
    }
    // self-loop (weight dinv[i]) and global factor dinv[i]
    float di = dinv[i], sv = s1[i];
    #pragma unroll
    for (int f = 0; f < HD; ++f)
        acc[f] = di * fmaf(di, fmaxf(fmaf(sv, w1[f], bb1[f]), 0.0f), acc[f]);
    // epilogue: h2 = relu(acc @ W2 + b2); out = h2 @ Wfc + bfc
    float o0 = bfc[0], o1 = bfc[1], o2 = bfc[2], o3 = bfc[3];
    #pragma unroll
    for (int f2 = 0; f2 < HD; ++f2) {
        float h = b2[f2];
        #pragma unroll
        for (int k = 0; k < HD; ++k) h = fmaf(acc[k], W2[k * HD + f2], h);
        h = fmaxf(h, 0.0f);
        o0 = fmaf(h, Wfc[f2 * NC + 0], o0);
        o1 = fmaf(h, Wfc[f2 * NC + 1], o1);
        o2 = fmaf(h, Wfc[f2 * NC + 2], o2);
        o3 = fmaf(h, Wfc[f2 * NC + 3], o3);
    }
    ((float4*)out)[i] = make_float4(o0, o1, o2, o3);
}

extern "C" void kernel_launch(void* const* d_in, const int* in_sizes, int n_in,
                              void* d_out, int out_size, void* d_ws, size_t ws_size,
                              hipStream_t stream) {
    const float* x   = (const float*)d_in[0];
    const int*   ei  = (const int*)d_in[1];
    const float* W1  = (const float*)d_in[2];
    const float* b1  = (const float*)d_in[3];
    const float* W2  = (const float*)d_in[4];
    const float* b2  = (const float*)d_in[5];
    const float* Wfc = (const float*)d_in[6];
    const float* bfc = (const float*)d_in[7];
    float* out = (float*)d_out;

    const int N = in_sizes[0];
    const int E = in_sizes[1] / 2;
    const int* row = ei;
    const int* col = ei + E;

    // workspace layout (bytes)
    char* ws = (char*)d_ws;
    int*   cnt  = (int*)(ws);                            // N
    int*   off  = (int*)(ws + (size_t)N * 4);            // N
    int*   fill = (int*)(ws + (size_t)N * 8);            // N
    float* dinv = (float*)(ws + (size_t)N * 12);         // N
    float* dx   = (float*)(ws + (size_t)N * 16);         // N
    float* s1   = (float*)(ws + (size_t)N * 20);         // N
    int*   bsum = (int*)(ws + (size_t)N * 24);           // 256 (pad 1KB)
    int*   csr  = (int*)(ws + (size_t)N * 24 + 1024);    // E

    hipMemsetAsync(cnt, 0, (size_t)N * 4, stream);

    const int B = 256;
    const int NBLK = (N + CHUNK - 1) / CHUNK;  // 123 for N=250k (<=256 required)

    k_degree<<<(E + B - 1) / B, B, 0, stream>>>(col, cnt, E);
    k_dinv<<<(N + B - 1) / B, B, 0, stream>>>(cnt, x, dinv, dx, N);
    k_scan1<<<NBLK, SCAN_B, 0, stream>>>(cnt, off, bsum, N);
    k_scan2<<<1, SCAN_B, 0, stream>>>(bsum, NBLK);
    k_scan3<<<(N + B - 1) / B, B, 0, stream>>>(off, bsum, fill, N);
    k_build<<<(E + B - 1) / B, B, 0, stream>>>(row, col, fill, csr, E);
    k_s1<<<(N + B - 1) / B, B, 0, stream>>>(off, cnt, csr, dinv, dx, s1, N);
    k_agg_out<<<(N + B - 1) / B, B, 0, stream>>>(off, cnt, csr, dinv, s1,
                                                 W1, b1, W2, b2, Wfc, bfc, out, N);
}